// Round 5
// baseline (3479.137 us; speedup 1.0000x reference)
//
#include <hip/hip_runtime.h>
#include <cstdint>
#include <cstddef>

#define NNODES 100000
#define FIN    512
#define HID    256
#define NCLS   64
#define KSTEPS 10
#define ALPHA  0.1f

// region-based CSR build
#define REGSH  9                 // region = dst >> 9 (512 nodes)
#define REGN   512
#define NREG   196               // ceil(100000/512)
#define RCAP   19456             // mean 16384, sigma ~128 -> +24 sigma
#define TILE   8192              // edges per pass1 block

// src-range phases for L2-resident propagation
#define NPARTS  4
#define PART_SZ 25000            // 3.2 MB of g per part (<= 4 MB per-XCD L2)
#define PBYTES  3200000          // PART_SZ * NCLS * 2
#define NPW     16               // nodes per wave
#define PROPB   1563             // ceil(100000 / (4*16)) blocks; ~6/CU co-resident
#define NSLICE  196              // prefetch slices per part (PROPB/8, rounded up)
#define SLB     16336            // bytes per slice (196*16336 >= PBYTES)

typedef __bf16 bf16;
typedef __attribute__((ext_vector_type(4))) __bf16 bf16x4;
typedef __attribute__((ext_vector_type(8))) __bf16 bf16x8;
typedef __attribute__((ext_vector_type(4))) float f32x4;

// ---------------- transpose + f32->bf16 convert for weights ----------------
__global__ void transpose_bf16(const float* __restrict__ W, bf16* __restrict__ Wt,
                               int K, int N) {
  int idx = blockIdx.x * 256 + threadIdx.x;
  if (idx >= K * N) return;
  int k = idx / N, n = idx % N;
  Wt[(size_t)n * K + k] = (bf16)W[idx];
}

// ---------------- GEMM1: h1 = relu(feat @ w1t^T + b1), BM=64 BN=256 ----------------
__global__ __launch_bounds__(256)
void mfma_gemm1(const float* __restrict__ A, const bf16* __restrict__ Bt,
                const float* __restrict__ bias, bf16* __restrict__ C, int M) {
  __shared__ bf16 sm[25600];     // [As0 2560][As1 2560][Bs0 10240][Bs1 10240]
  const int tid  = threadIdx.x;
  const int lane = tid & 63;
  const int wave = tid >> 6;       // n-quarter (64 cols each)
  const int row0 = blockIdx.x * 64;
  const int l15  = lane & 15;
  const int quad = lane >> 4;

  f32x4 acc[4][4] = {};
  float4 areg[2];
  bf16x8 breg[4];

  int arow[2], acol[2], brow[4], bcol[4];
#pragma unroll
  for (int i = 0; i < 2; ++i) { int idx = tid + i * 256; arow[i] = idx >> 3; acol[i] = (idx & 7) * 4; }
#pragma unroll
  for (int i = 0; i < 4; ++i) { int idx = tid + i * 256; brow[i] = idx >> 2; bcol[i] = (idx & 3) * 8; }

  auto loadAB = [&](int k0) {
#pragma unroll
    for (int i = 0; i < 2; ++i) {
      int gr = row0 + arow[i];
      areg[i] = make_float4(0.f, 0.f, 0.f, 0.f);
      if (gr < M) areg[i] = *(const float4*)&A[(size_t)gr * FIN + k0 + acol[i]];
    }
#pragma unroll
    for (int i = 0; i < 4; ++i)
      breg[i] = *(const bf16x8*)&Bt[(size_t)brow[i] * FIN + k0 + bcol[i]];
  };
  auto storeAB = [&](int buf) {
    const int ao = buf * 2560, bo = 5120 + buf * 10240;
#pragma unroll
    for (int i = 0; i < 2; ++i) {
      bf16x4 b;
      b[0] = (bf16)areg[i].x; b[1] = (bf16)areg[i].y;
      b[2] = (bf16)areg[i].z; b[3] = (bf16)areg[i].w;
      *(bf16x4*)&sm[ao + arow[i] * 40 + acol[i]] = b;
    }
#pragma unroll
    for (int i = 0; i < 4; ++i)
      *(bf16x8*)&sm[bo + brow[i] * 40 + bcol[i]] = breg[i];
  };

  loadAB(0);
  storeAB(0);
  __syncthreads();

  for (int kk = 0; kk < 16; ++kk) {
    const int cur = kk & 1;
    if (kk < 15) loadAB((kk + 1) * 32);          // issue next-tile loads early
    const int ao = cur * 2560, bo = 5120 + cur * 10240;
    bf16x8 af[4], bfr[4];
#pragma unroll
    for (int mt = 0; mt < 4; ++mt)
      af[mt] = *(const bf16x8*)&sm[ao + (mt * 16 + l15) * 40 + quad * 8];
#pragma unroll
    for (int nt = 0; nt < 4; ++nt)
      bfr[nt] = *(const bf16x8*)&sm[bo + (wave * 64 + nt * 16 + l15) * 40 + quad * 8];
#pragma unroll
    for (int mt = 0; mt < 4; ++mt)
#pragma unroll
      for (int nt = 0; nt < 4; ++nt)
        acc[mt][nt] = __builtin_amdgcn_mfma_f32_16x16x32_bf16(af[mt], bfr[nt],
                                                              acc[mt][nt], 0, 0, 0);
    if (kk < 15) storeAB(cur ^ 1);               // vmcnt wait lands after MFMAs
    __syncthreads();                             // single barrier per K-step
  }

  // epilogue: stage C tile in LDS, store coalesced full lines
#pragma unroll
  for (int nt = 0; nt < 4; ++nt) {
    int gc = wave * 64 + nt * 16 + l15;
    float bv = bias[gc];
#pragma unroll
    for (int mt = 0; mt < 4; ++mt)
#pragma unroll
      for (int r = 0; r < 4; ++r)
        sm[(mt * 16 + quad * 4 + r) * 264 + gc] = (bf16)fmaxf(acc[mt][nt][r] + bv, 0.f);
  }
  __syncthreads();
#pragma unroll
  for (int it = 0; it < 8; ++it) {
    int idx = tid + it * 256;
    int row = idx >> 5, c8 = (idx & 31) * 8;
    int gr = row0 + row;
    if (gr < M)
      *(bf16x8*)&C[(size_t)gr * HID + c8] = *(const bf16x8*)&sm[row * 264 + c8];
  }
}

// ---------------- GEMM2: g0 = norm .* (h1 @ w2t^T + b2), BM=128 BN=64 ----------------
__global__ __launch_bounds__(256)
void mfma_gemm2(const bf16* __restrict__ A, const bf16* __restrict__ Bt,
                const float* __restrict__ bias, const float* __restrict__ norm,
                bf16* __restrict__ g0, int M) {
  __shared__ bf16 As[128][40];
  __shared__ bf16 Bs[64][40];
  const int tid  = threadIdx.x;
  const int lane = tid & 63;
  const int wave = tid >> 6;
  const int wm = wave >> 1;
  const int wn = wave & 1;
  const int row0 = blockIdx.x * 128;
  const int l15  = lane & 15;
  const int quad = lane >> 4;

  f32x4 acc[4][2] = {};

  for (int k0 = 0; k0 < HID; k0 += 32) {
#pragma unroll
    for (int i = 0; i < 2; ++i) {
      int idx = tid + i * 256;
      int r = idx >> 2, k16 = idx & 3;
      int gr = row0 + r;
      bf16x8 v = {};
      if (gr < M) v = *(const bf16x8*)&A[(size_t)gr * HID + k0 + k16 * 8];
      *(bf16x8*)&As[r][k16 * 8] = v;
    }
    {
      int nrow = tid >> 2, k16 = tid & 3;
      bf16x8 v = *(const bf16x8*)&Bt[(size_t)nrow * HID + k0 + k16 * 8];
      *(bf16x8*)&Bs[nrow][k16 * 8] = v;
    }
    __syncthreads();

    bf16x8 af[4], bfr[2];
#pragma unroll
    for (int mt = 0; mt < 4; ++mt)
      af[mt] = *(const bf16x8*)&As[wm * 64 + mt * 16 + l15][quad * 8];
#pragma unroll
    for (int nt = 0; nt < 2; ++nt)
      bfr[nt] = *(const bf16x8*)&Bs[wn * 32 + nt * 16 + l15][quad * 8];
#pragma unroll
    for (int mt = 0; mt < 4; ++mt)
#pragma unroll
      for (int nt = 0; nt < 2; ++nt)
        acc[mt][nt] = __builtin_amdgcn_mfma_f32_16x16x32_bf16(af[mt], bfr[nt],
                                                              acc[mt][nt], 0, 0, 0);
    __syncthreads();
  }

#pragma unroll
  for (int nt = 0; nt < 2; ++nt) {
    int gc = wn * 32 + nt * 16 + l15;
    float bv = bias[gc];
#pragma unroll
    for (int mt = 0; mt < 4; ++mt)
#pragma unroll
      for (int r = 0; r < 4; ++r) {
        int gr = row0 + wm * 64 + mt * 16 + quad * 4 + r;
        if (gr < M) {
          float v = acc[mt][nt][r] + bv;
          g0[(size_t)gr * NCLS + gc] = (bf16)(norm[gr] * v);
        }
      }
  }
}

// ---------------- CSR pass 1: tile-local region binning (unchanged) ----------------
__global__ __launch_bounds__(256)
void csr_pass1(const int* __restrict__ src, const int* __restrict__ dst,
               unsigned* __restrict__ rcnt, unsigned* __restrict__ rdata, int E) {
  __shared__ unsigned hist[NREG];
  __shared__ unsigned lcur[NREG];
  const int e0 = blockIdx.x * TILE;
  const int n = min(TILE, E - e0);
  for (int t = threadIdx.x; t < NREG; t += 256) hist[t] = 0;
  __syncthreads();
  for (int i = threadIdx.x; i < n; i += 256)
    atomicAdd(&hist[(unsigned)dst[e0 + i] >> REGSH], 1u);
  __syncthreads();
  for (int t = threadIdx.x; t < NREG; t += 256) {
    unsigned v = hist[t];
    lcur[t] = v ? atomicAdd(&rcnt[t], v) : 0u;
  }
  __syncthreads();
  for (int i = threadIdx.x; i < n; i += 256) {
    int s = src[e0 + i], d = dst[e0 + i];
    unsigned r = (unsigned)d >> REGSH;
    unsigned p = atomicAdd(&lcur[r], 1u);
    rdata[(size_t)r * RCAP + p] = ((unsigned)s << REGSH) | ((unsigned)d & (REGN - 1u));
  }
}

// ---------------- CSR pass 2: per-region, (phase, node)-major col layout ----------------
// Emits start4[node*4+p] = (pos<<8)|cnt (cnt Poisson(8) <= 255) and norms.
__global__ __launch_bounds__(256)
void csr_pass2(const unsigned* __restrict__ rcnt, const unsigned* __restrict__ rdata,
               unsigned* __restrict__ colcur, float* __restrict__ norm,
               float* __restrict__ rnorm, float* __restrict__ norm2a,
               unsigned* __restrict__ start4, int* __restrict__ col) {
  __shared__ unsigned hist[NPARTS * REGN];    // [p][node]
  __shared__ unsigned excl[NPARTS * REGN];    // exclusive offsets, then cursors
  __shared__ unsigned partial[256];
  __shared__ unsigned rbase_s;
  const int r = blockIdx.x;
  const int tid = threadIdx.x;
  const unsigned cnt = rcnt[r];
  const unsigned* data = &rdata[(size_t)r * RCAP];

  for (int i = tid; i < NPARTS * REGN; i += 256) hist[i] = 0;
  __syncthreads();
  for (unsigned i = tid; i < cnt; i += 256) {
    unsigned v = data[i];
    unsigned s = v >> REGSH;
    atomicAdd(&hist[(s / PART_SZ) * REGN + (v & (REGN - 1u))], 1u);
  }
  __syncthreads();

  // block scan over 2048 elements in (p-major, node-minor) order
  const int base_e = tid * 8;
  unsigned mysum = 0;
#pragma unroll
  for (int k = 0; k < 8; ++k) mysum += hist[base_e + k];
  partial[tid] = mysum;
  __syncthreads();
  for (int o = 1; o < 256; o <<= 1) {
    unsigned v = partial[tid];
    unsigned t2 = (tid >= o) ? partial[tid - o] : 0u;
    __syncthreads();
    partial[tid] = v + t2;
    __syncthreads();
  }
  if (tid == 255) rbase_s = atomicAdd(colcur, partial[255]);
  __syncthreads();
  unsigned run = (tid ? partial[tid - 1] : 0u) + rbase_s;
#pragma unroll
  for (int k = 0; k < 8; ++k) {
    excl[base_e + k] = run;
    run += hist[base_e + k];
  }
  __syncthreads();

  for (int nl = tid; nl < REGN; nl += 256) {
    int node = (r << REGSH) + nl;
    if (node < NNODES) {
      unsigned deg = 0;
#pragma unroll
      for (int p = 0; p < NPARTS; ++p) {
        unsigned c = hist[p * REGN + nl];
        start4[(size_t)node * NPARTS + p] = (excl[p * REGN + nl] << 8) | c;
        deg += c;
      }
      float dp1 = (float)(deg + 1u);
      norm[node] = rsqrtf(dp1); rnorm[node] = sqrtf(dp1);
      norm2a[node] = (1.0f - ALPHA) / dp1;
    }
  }
  __syncthreads();

  for (unsigned i = tid; i < cnt; i += 256) {
    unsigned v = data[i];
    unsigned s = v >> REGSH;
    unsigned pos = atomicAdd(&excl[(s / PART_SZ) * REGN + (v & (REGN - 1u))], 1u);
    col[pos] = (int)s;
  }
}

// ---------------- phased pull propagation ----------------
// All co-resident blocks sweep src parts p=0..3; per phase, block b prefetches
// slice (b>>3) of the part (round-robin XCD dispatch => each XCD's blocks cover
// the part exactly once => gathers hit that XCD's L2).
__global__ __launch_bounds__(256, 6)
void appnp_pull_phases(const bf16* __restrict__ g, const bf16* __restrict__ g0,
                       const float* __restrict__ norm2a,
                       const unsigned* __restrict__ start4,
                       const int* __restrict__ col, bf16* __restrict__ g_new) {
  const int tid  = threadIdx.x;
  const int wid  = blockIdx.x * 4 + (tid >> 6);
  const int lane = tid & 63;
  const int node0 = wid * NPW;
  const int slice = blockIdx.x >> 3;           // 0..195

  float acc[NPW];
#pragma unroll
  for (int t = 0; t < NPW; ++t) acc[t] = 0.f;

  for (int p = 0; p < NPARTS; ++p) {
    // ---- prefetch this block's slice of part p into the local XCD L2 ----
    {
      const char* pb = (const char*)g + (size_t)p * PBYTES;
      const size_t s0 = (size_t)slice * SLB;
      for (int i = tid; i < SLB / 16; i += 256) {
        size_t o = s0 + (size_t)i * 16;
        if (o < PBYTES) {
          float4 v = *(const float4*)(pb + o);
          asm volatile("" :: "v"(v.x), "v"(v.y), "v"(v.z), "v"(v.w));
        }
      }
    }
    __syncthreads();   // keep the block's waves phase-aligned

    // ---- preload this wave's 16 run descriptors for phase p ----
    unsigned sv[NPW];
#pragma unroll
    for (int t = 0; t < NPW; ++t) {
      int node = node0 + t;
      sv[t] = (node < NNODES) ? start4[(size_t)node * NPARTS + p] : 0u;
    }

    // ---- gather: 8-deep main + one branchless predicated 8-group tail ----
#pragma unroll
    for (int t = 0; t < NPW; ++t) {
      unsigned j = sv[t] >> 8;
      const unsigned j1 = j + (sv[t] & 255u);
      float a = 0.f;
      for (; j + 8 <= j1; j += 8) {
        int c0 = col[j],     c1 = col[j + 1], c2 = col[j + 2], c3 = col[j + 3];
        int c4 = col[j + 4], c5 = col[j + 5], c6 = col[j + 6], c7 = col[j + 7];
        float x0 = (float)g[(size_t)c0 * NCLS + lane];
        float x1 = (float)g[(size_t)c1 * NCLS + lane];
        float x2 = (float)g[(size_t)c2 * NCLS + lane];
        float x3 = (float)g[(size_t)c3 * NCLS + lane];
        float x4 = (float)g[(size_t)c4 * NCLS + lane];
        float x5 = (float)g[(size_t)c5 * NCLS + lane];
        float x6 = (float)g[(size_t)c6 * NCLS + lane];
        float x7 = (float)g[(size_t)c7 * NCLS + lane];
        a += ((x0 + x1) + (x2 + x3)) + ((x4 + x5) + (x6 + x7));
      }
      if (j < j1) {
        const unsigned last = j1 - 1;
        int cc[8];
        float m[8];
#pragma unroll
        for (int u = 0; u < 8; ++u) {
          unsigned e = j + u;
          cc[u] = col[e < j1 ? e : last];
          m[u] = (e < j1) ? 1.f : 0.f;
        }
        float s = 0.f;
#pragma unroll
        for (int u = 0; u < 8; ++u)
          s += m[u] * (float)g[(size_t)cc[u] * NCLS + lane];
        a += s;
      }
      acc[t] += a;
    }
  }

  // ---- epilogue ----
#pragma unroll
  for (int t = 0; t < NPW; ++t) {
    int node = node0 + t;
    if (node < NNODES) {
      size_t idx = (size_t)node * NCLS + lane;
      float a = acc[t] + (float)g[idx];                 // self-loop
      g_new[idx] = (bf16)fmaf(norm2a[node], a, ALPHA * (float)g0[idx]);
    }
  }
}

// ---------------- log_softmax on h = g .* rnorm ----------------
__global__ __launch_bounds__(256)
void log_softmax_k(const bf16* __restrict__ g, const float* __restrict__ rnorm,
                   float* __restrict__ out, int n) {
  int wave = threadIdx.x >> 6;
  int lane = threadIdx.x & 63;
  int row = blockIdx.x * 4 + wave;
  if (row >= n) return;
  float x = (float)g[(size_t)row * NCLS + lane] * rnorm[row];
  float m = x;
#pragma unroll
  for (int o = 32; o; o >>= 1) m = fmaxf(m, __shfl_xor(m, o, 64));
  float ex = expf(x - m);
  float s = ex;
#pragma unroll
  for (int o = 32; o; o >>= 1) s += __shfl_xor(s, o, 64);
  out[(size_t)row * NCLS + lane] = x - m - logf(s);
}

// ---------------- launch ----------------
extern "C" void kernel_launch(void* const* d_in, const int* in_sizes, int n_in,
                              void* d_out, int out_size, void* d_ws, size_t ws_size,
                              hipStream_t stream) {
  (void)n_in; (void)out_size; (void)ws_size;
  const float* feat = (const float*)d_in[0];
  const float* w1   = (const float*)d_in[1];
  const float* b1   = (const float*)d_in[2];
  const float* w2   = (const float*)d_in[3];
  const float* b2   = (const float*)d_in[4];
  const int*   src  = (const int*)d_in[5];
  const int*   dst  = (const int*)d_in[6];
  const int E = in_sizes[5];
  float* out = (float*)d_out;

  // workspace layout (~96 MB)
  char* ws = (char*)d_ws;
  size_t off = 0;
  float* norm   = (float*)(ws + off);         off += ((size_t)NNODES * 4 + 255) & ~(size_t)255;
  float* rnorm  = (float*)(ws + off);         off += ((size_t)NNODES * 4 + 255) & ~(size_t)255;
  float* norm2a = (float*)(ws + off);         off += ((size_t)NNODES * 4 + 255) & ~(size_t)255;
  unsigned* start4 = (unsigned*)(ws + off);   off += ((size_t)NNODES * NPARTS * 4 + 255) & ~(size_t)255;
  unsigned* colcur = (unsigned*)(ws + off);   off += 256;
  unsigned* rcnt   = (unsigned*)(ws + off);   off += ((size_t)NREG * 4 + 255) & ~(size_t)255;
  bf16* g0 = (bf16*)(ws + off);               off += (size_t)NNODES * NCLS * 2;   // 12.8 MB
  // X region (51.2 MB): h1b [N][HID] bf16 during MLP; pb0/pb1 alias it (written
  // only after GEMM2 consumed h1b).
  char* X = ws + off;                         off += (size_t)NNODES * HID * 2;
  bf16* h1b = (bf16*)X;
  bf16* pb0 = (bf16*)X;
  bf16* pb1 = (bf16*)(X + (size_t)NNODES * NCLS * 2);
  int*  col = (int*)(ws + off);               off += ((size_t)E * 4 + 255) & ~(size_t)255;  // 12.8 MB
  unsigned* rdata = (unsigned*)(ws + off);    off += (size_t)NREG * RCAP * 4;     // 15.3 MB
  bf16* w1t = (bf16*)(ws + off);              off += ((size_t)HID * FIN * 2 + 255) & ~(size_t)255;
  bf16* w2t = (bf16*)(ws + off);              off += ((size_t)NCLS * HID * 2 + 255) & ~(size_t)255;

  // ---- CSR pass 1 ----
  hipMemsetAsync(rcnt, 0, (size_t)NREG * 4, stream);
  hipMemsetAsync(colcur, 0, 256, stream);
  csr_pass1<<<(E + TILE - 1) / TILE, 256, 0, stream>>>(src, dst, rcnt, rdata, E);

  // ---- weight transpose/convert (tiny) ----
  transpose_bf16<<<(FIN * HID + 255) / 256, 256, 0, stream>>>(w1, w1t, FIN, HID);
  transpose_bf16<<<(HID * NCLS + 255) / 256, 256, 0, stream>>>(w2, w2t, HID, NCLS);

  // ---- GEMM1 (A fetched once, pipelined dbuf) ----
  mfma_gemm1<<<(NNODES + 63) / 64, 256, 0, stream>>>(feat, w1t, b1, h1b, NNODES);

  // ---- CSR pass 2 (norm needed by GEMM2 epilogue) ----
  csr_pass2<<<NREG, 256, 0, stream>>>(rcnt, rdata, colcur, norm, rnorm,
                                      norm2a, start4, col);

  // ---- GEMM2 with fused norm-scaling: writes g0 = norm .* h0 ----
  mfma_gemm2<<<(NNODES + 127) / 128, 256, 0, stream>>>(h1b, w2t, b2, norm, g0, NNODES);

  // ---- APPNP propagation: phased pull with per-phase L2 prefetch ----
  const bf16* cur = g0;
  bf16* bufs[2] = {pb0, pb1};
  for (int k = 0; k < KSTEPS; ++k) {
    bf16* nxt = bufs[k & 1];
    appnp_pull_phases<<<PROPB, 256, 0, stream>>>(cur, g0, norm2a, start4, col, nxt);
    cur = nxt;
  }

  // ---- log_softmax (unscale by rnorm) ----
  log_softmax_k<<<(NNODES + 3) / 4, 256, 0, stream>>>(cur, rnorm, out, NNODES);
}

// Round 6
// 1251.665 us; speedup vs baseline: 2.7796x; 2.7796x over previous
//
#include <hip/hip_runtime.h>
#include <cstdint>
#include <cstddef>

#define NNODES 100000
#define FIN    512
#define HID    256
#define NCLS   64
#define KSTEPS 10
#define ALPHA  0.1f

// region-based CSR build
#define REGSH  9                 // region = dst >> 9 (512 nodes)
#define REGN   512
#define NREG   196               // ceil(100000/512)
#define RCAP   19456             // mean 16384, sigma ~128 -> +24 sigma
#define TILE   8192              // edges per pass1 block

typedef __bf16 bf16;
typedef __attribute__((ext_vector_type(4))) __bf16 bf16x4;
typedef __attribute__((ext_vector_type(8))) __bf16 bf16x8;
typedef __attribute__((ext_vector_type(4))) float f32x4;

// ---------------- transpose + f32->bf16 convert for weights ----------------
__global__ void transpose_bf16(const float* __restrict__ W, bf16* __restrict__ Wt,
                               int K, int N) {
  int idx = blockIdx.x * 256 + threadIdx.x;
  if (idx >= K * N) return;
  int k = idx / N, n = idx % N;
  Wt[(size_t)n * K + k] = (bf16)W[idx];
}

// ---------------- GEMM1: h1 = relu(feat @ w1t^T + b1), BM=128 BN=256, 8 waves ----
// Double-buffered LDS, one barrier per K-step, loads issued before compute.
// 2 blocks/CU (61.4 KB LDS) -> independent blocks desynchronize the load convoy.
__global__ __launch_bounds__(512, 4)
void mfma_gemm1(const float* __restrict__ A, const bf16* __restrict__ Bt,
                const float* __restrict__ bias, bf16* __restrict__ C, int M) {
  __shared__ bf16 sm[30720];     // [As0 5120][As1 5120][Bs0 10240][Bs1 10240] elems
  const int tid  = threadIdx.x;
  const int lane = tid & 63;
  const int wave = tid >> 6;       // 0..7
  const int wm   = wave >> 2;      // row half (64 rows)
  const int wn   = wave & 3;       // col quarter (64 cols)
  const int row0 = blockIdx.x * 128;
  const int l15  = lane & 15;
  const int quad = lane >> 4;

  f32x4 acc[4][4] = {};
  float4 areg[2];
  bf16x8 breg[2];

  int arow[2], acol[2], brow[2], bcol[2];
#pragma unroll
  for (int i = 0; i < 2; ++i) { int idx = tid + i * 512; arow[i] = idx >> 3; acol[i] = (idx & 7) * 4; }
#pragma unroll
  for (int i = 0; i < 2; ++i) { int idx = tid + i * 512; brow[i] = idx >> 2; bcol[i] = (idx & 3) * 8; }

  auto loadAB = [&](int k0) {
#pragma unroll
    for (int i = 0; i < 2; ++i) {
      int gr = row0 + arow[i];
      areg[i] = make_float4(0.f, 0.f, 0.f, 0.f);
      if (gr < M) areg[i] = *(const float4*)&A[(size_t)gr * FIN + k0 + acol[i]];
    }
#pragma unroll
    for (int i = 0; i < 2; ++i)
      breg[i] = *(const bf16x8*)&Bt[(size_t)brow[i] * FIN + k0 + bcol[i]];
  };
  auto storeAB = [&](int buf) {
    const int ao = buf * 5120, bo = 10240 + buf * 10240;
#pragma unroll
    for (int i = 0; i < 2; ++i) {
      bf16x4 b;
      b[0] = (bf16)areg[i].x; b[1] = (bf16)areg[i].y;
      b[2] = (bf16)areg[i].z; b[3] = (bf16)areg[i].w;
      *(bf16x4*)&sm[ao + arow[i] * 40 + acol[i]] = b;
    }
#pragma unroll
    for (int i = 0; i < 2; ++i)
      *(bf16x8*)&sm[bo + brow[i] * 40 + bcol[i]] = breg[i];
  };

  loadAB(0);
  storeAB(0);
  __syncthreads();

  for (int kk = 0; kk < 16; ++kk) {
    const int cur = kk & 1;
    if (kk < 15) loadAB((kk + 1) * 32);          // issue next-tile loads early
    const int ao = cur * 5120, bo = 10240 + cur * 10240;
    bf16x8 af[4], bfr[4];
#pragma unroll
    for (int mt = 0; mt < 4; ++mt)
      af[mt] = *(const bf16x8*)&sm[ao + (wm * 64 + mt * 16 + l15) * 40 + quad * 8];
#pragma unroll
    for (int nt = 0; nt < 4; ++nt)
      bfr[nt] = *(const bf16x8*)&sm[bo + (wn * 64 + nt * 16 + l15) * 40 + quad * 8];
#pragma unroll
    for (int mt = 0; mt < 4; ++mt)
#pragma unroll
      for (int nt = 0; nt < 4; ++nt)
        acc[mt][nt] = __builtin_amdgcn_mfma_f32_16x16x32_bf16(af[mt], bfr[nt],
                                                              acc[mt][nt], 0, 0, 0);
    if (kk < 15) storeAB(cur ^ 1);               // vmcnt wait lands after MFMAs
    __syncthreads();                             // single barrier per K-step
  }

  // epilogue: two 64-row halves staged in LDS, full-line coalesced stores
#pragma unroll
  for (int h = 0; h < 2; ++h) {
    if (wm == h) {
#pragma unroll
      for (int nt = 0; nt < 4; ++nt) {
        int gc = wn * 64 + nt * 16 + l15;
        float bv = bias[gc];
#pragma unroll
        for (int mt = 0; mt < 4; ++mt)
#pragma unroll
          for (int r = 0; r < 4; ++r)
            sm[(mt * 16 + quad * 4 + r) * 264 + gc] = (bf16)fmaxf(acc[mt][nt][r] + bv, 0.f);
      }
    }
    __syncthreads();
#pragma unroll
    for (int it = 0; it < 4; ++it) {
      int idx = tid + it * 512;
      int row = idx >> 5, c8 = (idx & 31) * 8;
      int gr = row0 + h * 64 + row;
      if (gr < M)
        *(bf16x8*)&C[(size_t)gr * HID + c8] = *(const bf16x8*)&sm[row * 264 + c8];
    }
    __syncthreads();
  }
}

// ---------------- GEMM2: g0 = norm .* (h1 @ w2t^T + b2), BM=128 BN=64 ----------------
__global__ __launch_bounds__(256)
void mfma_gemm2(const bf16* __restrict__ A, const bf16* __restrict__ Bt,
                const float* __restrict__ bias, const float* __restrict__ norm,
                bf16* __restrict__ g0, int M) {
  __shared__ bf16 As[128][40];
  __shared__ bf16 Bs[64][40];
  const int tid  = threadIdx.x;
  const int lane = tid & 63;
  const int wave = tid >> 6;
  const int wm = wave >> 1;
  const int wn = wave & 1;
  const int row0 = blockIdx.x * 128;
  const int l15  = lane & 15;
  const int quad = lane >> 4;

  f32x4 acc[4][2] = {};

  for (int k0 = 0; k0 < HID; k0 += 32) {
#pragma unroll
    for (int i = 0; i < 2; ++i) {
      int idx = tid + i * 256;
      int r = idx >> 2, k16 = idx & 3;
      int gr = row0 + r;
      bf16x8 v = {};
      if (gr < M) v = *(const bf16x8*)&A[(size_t)gr * HID + k0 + k16 * 8];
      *(bf16x8*)&As[r][k16 * 8] = v;
    }
    {
      int nrow = tid >> 2, k16 = tid & 3;
      bf16x8 v = *(const bf16x8*)&Bt[(size_t)nrow * HID + k0 + k16 * 8];
      *(bf16x8*)&Bs[nrow][k16 * 8] = v;
    }
    __syncthreads();

    bf16x8 af[4], bfr[2];
#pragma unroll
    for (int mt = 0; mt < 4; ++mt)
      af[mt] = *(const bf16x8*)&As[wm * 64 + mt * 16 + l15][quad * 8];
#pragma unroll
    for (int nt = 0; nt < 2; ++nt)
      bfr[nt] = *(const bf16x8*)&Bs[wn * 32 + nt * 16 + l15][quad * 8];
#pragma unroll
    for (int mt = 0; mt < 4; ++mt)
#pragma unroll
      for (int nt = 0; nt < 2; ++nt)
        acc[mt][nt] = __builtin_amdgcn_mfma_f32_16x16x32_bf16(af[mt], bfr[nt],
                                                              acc[mt][nt], 0, 0, 0);
    __syncthreads();
  }

#pragma unroll
  for (int nt = 0; nt < 2; ++nt) {
    int gc = wn * 32 + nt * 16 + l15;
    float bv = bias[gc];
#pragma unroll
    for (int mt = 0; mt < 4; ++mt)
#pragma unroll
      for (int r = 0; r < 4; ++r) {
        int gr = row0 + wm * 64 + mt * 16 + quad * 4 + r;
        if (gr < M) {
          float v = acc[mt][nt][r] + bv;
          g0[(size_t)gr * NCLS + gc] = (bf16)(norm[gr] * v);
        }
      }
  }
}

// ---------------- CSR pass 1: tile-local region binning ----------------
__global__ __launch_bounds__(256)
void csr_pass1(const int* __restrict__ src, const int* __restrict__ dst,
               unsigned* __restrict__ rcnt, unsigned* __restrict__ rdata, int E) {
  __shared__ unsigned hist[NREG];
  __shared__ unsigned lcur[NREG];
  const int e0 = blockIdx.x * TILE;
  const int n = min(TILE, E - e0);
  for (int t = threadIdx.x; t < NREG; t += 256) hist[t] = 0;
  __syncthreads();
  for (int i = threadIdx.x; i < n; i += 256)
    atomicAdd(&hist[(unsigned)dst[e0 + i] >> REGSH], 1u);
  __syncthreads();
  for (int t = threadIdx.x; t < NREG; t += 256) {
    unsigned v = hist[t];
    lcur[t] = v ? atomicAdd(&rcnt[t], v) : 0u;
  }
  __syncthreads();
  for (int i = threadIdx.x; i < n; i += 256) {
    int s = src[e0 + i], d = dst[e0 + i];
    unsigned r = (unsigned)d >> REGSH;
    unsigned p = atomicAdd(&lcur[r], 1u);
    rdata[(size_t)r * RCAP + p] = ((unsigned)s << REGSH) | ((unsigned)d & (REGN - 1u));
  }
}

// ---------------- CSR pass 2: per-region node CSR ----------------
__global__ __launch_bounds__(256)
void csr_pass2(const unsigned* __restrict__ rcnt, const unsigned* __restrict__ rdata,
               unsigned* __restrict__ colcur, float* __restrict__ norm,
               float* __restrict__ rnorm, float* __restrict__ norm2a,
               unsigned* __restrict__ startp, unsigned* __restrict__ endp,
               int* __restrict__ col) {
  __shared__ unsigned hist[REGN];
  __shared__ unsigned pairs[256];
  __shared__ unsigned lcur[REGN];
  __shared__ unsigned rbase_s;
  const int r = blockIdx.x;
  const int tid = threadIdx.x;
  const unsigned cnt = rcnt[r];
  const unsigned* data = &rdata[(size_t)r * RCAP];

  hist[tid] = 0; hist[tid + 256] = 0;
  __syncthreads();
  for (unsigned i = tid; i < cnt; i += 256)
    atomicAdd(&hist[data[i] & (REGN - 1u)], 1u);
  __syncthreads();

  const unsigned a = hist[2 * tid], b = hist[2 * tid + 1];
  pairs[tid] = a + b;
  __syncthreads();
  for (int o = 1; o < 256; o <<= 1) {
    unsigned v = pairs[tid];
    unsigned t2 = (tid >= o) ? pairs[tid - o] : 0u;
    __syncthreads();
    pairs[tid] = v + t2;
    __syncthreads();
  }
  if (tid == 255) rbase_s = atomicAdd(colcur, pairs[255]);
  __syncthreads();

  const unsigned excl = (tid ? pairs[tid - 1] : 0u) + rbase_s;
  {
    int node = (r << REGSH) + 2 * tid;
    unsigned st0 = excl, st1 = excl + a;
    lcur[2 * tid] = st0; lcur[2 * tid + 1] = st1;
    if (node < NNODES) {
      startp[node] = st0; endp[node] = st0 + a;
      float dp1 = (float)(a + 1u);
      norm[node] = rsqrtf(dp1); rnorm[node] = sqrtf(dp1);
      norm2a[node] = (1.0f - ALPHA) / dp1;
    }
    if (node + 1 < NNODES) {
      startp[node + 1] = st1; endp[node + 1] = st1 + b;
      float dp1 = (float)(b + 1u);
      norm[node + 1] = rsqrtf(dp1); rnorm[node + 1] = sqrtf(dp1);
      norm2a[node + 1] = (1.0f - ALPHA) / dp1;
    }
  }
  __syncthreads();
  for (unsigned i = tid; i < cnt; i += 256) {
    unsigned v = data[i];
    unsigned p = atomicAdd(&lcur[v & (REGN - 1u)], 1u);
    col[p] = (int)(v >> REGSH);
  }
}

// ---------------- pull propagation on scaled state g = norm.*h ----------------
__global__ __launch_bounds__(256)
void appnp_pull_g(const bf16* __restrict__ g, const bf16* __restrict__ g0,
                  const float* __restrict__ norm2a,
                  const unsigned* __restrict__ start, const unsigned* __restrict__ endp,
                  const int* __restrict__ col, bf16* __restrict__ g_new) {
  const int wid = __builtin_amdgcn_readfirstlane((blockIdx.x * 256 + (int)threadIdx.x) >> 6);
  const int lane = threadIdx.x & 63;
  unsigned j = start[wid];
  const unsigned j1 = endp[wid];
  float acc = 0.f;

  for (; j + 16 <= j1; j += 16) {
    int c[16];
#pragma unroll
    for (int u = 0; u < 16; ++u) c[u] = col[j + u];
    float x[16];
#pragma unroll
    for (int u = 0; u < 16; ++u) x[u] = (float)g[(size_t)c[u] * NCLS + lane];
    acc += (((x[0] + x[1]) + (x[2] + x[3])) + ((x[4] + x[5]) + (x[6] + x[7])))
         + (((x[8] + x[9]) + (x[10] + x[11])) + ((x[12] + x[13]) + (x[14] + x[15])));
  }
  for (; j + 8 <= j1; j += 8) {
    int c0 = col[j], c1 = col[j + 1], c2 = col[j + 2], c3 = col[j + 3];
    int c4 = col[j + 4], c5 = col[j + 5], c6 = col[j + 6], c7 = col[j + 7];
    float v0 = (float)g[(size_t)c0 * NCLS + lane];
    float v1 = (float)g[(size_t)c1 * NCLS + lane];
    float v2 = (float)g[(size_t)c2 * NCLS + lane];
    float v3 = (float)g[(size_t)c3 * NCLS + lane];
    float v4 = (float)g[(size_t)c4 * NCLS + lane];
    float v5 = (float)g[(size_t)c5 * NCLS + lane];
    float v6 = (float)g[(size_t)c6 * NCLS + lane];
    float v7 = (float)g[(size_t)c7 * NCLS + lane];
    acc += ((v0 + v1) + (v2 + v3)) + ((v4 + v5) + (v6 + v7));
  }
  for (; j < j1; ++j)
    acc += (float)g[(size_t)col[j] * NCLS + lane];

  const size_t idx = (size_t)wid * NCLS + lane;
  acc += (float)g[idx];                               // self-loop
  g_new[idx] = (bf16)fmaf(norm2a[wid], acc, ALPHA * (float)g0[idx]);
}

// ---------------- log_softmax on h = g .* rnorm ----------------
__global__ __launch_bounds__(256)
void log_softmax_k(const bf16* __restrict__ g, const float* __restrict__ rnorm,
                   float* __restrict__ out, int n) {
  int wave = threadIdx.x >> 6;
  int lane = threadIdx.x & 63;
  int row = blockIdx.x * 4 + wave;
  if (row >= n) return;
  float x = (float)g[(size_t)row * NCLS + lane] * rnorm[row];
  float m = x;
#pragma unroll
  for (int o = 32; o; o >>= 1) m = fmaxf(m, __shfl_xor(m, o, 64));
  float ex = expf(x - m);
  float s = ex;
#pragma unroll
  for (int o = 32; o; o >>= 1) s += __shfl_xor(s, o, 64);
  out[(size_t)row * NCLS + lane] = x - m - logf(s);
}

// ---------------- launch ----------------
extern "C" void kernel_launch(void* const* d_in, const int* in_sizes, int n_in,
                              void* d_out, int out_size, void* d_ws, size_t ws_size,
                              hipStream_t stream) {
  (void)n_in; (void)out_size; (void)ws_size;
  const float* feat = (const float*)d_in[0];
  const float* w1   = (const float*)d_in[1];
  const float* b1   = (const float*)d_in[2];
  const float* w2   = (const float*)d_in[3];
  const float* b2   = (const float*)d_in[4];
  const int*   src  = (const int*)d_in[5];
  const int*   dst  = (const int*)d_in[6];
  const int E = in_sizes[5];
  float* out = (float*)d_out;

  // workspace layout (~95 MB)
  char* ws = (char*)d_ws;
  size_t off = 0;
  float* norm   = (float*)(ws + off);         off += ((size_t)NNODES * 4 + 255) & ~(size_t)255;
  float* rnorm  = (float*)(ws + off);         off += ((size_t)NNODES * 4 + 255) & ~(size_t)255;
  float* norm2a = (float*)(ws + off);         off += ((size_t)NNODES * 4 + 255) & ~(size_t)255;
  unsigned* startp = (unsigned*)(ws + off);   off += ((size_t)NNODES * 4 + 255) & ~(size_t)255;
  unsigned* endp   = (unsigned*)(ws + off);   off += ((size_t)NNODES * 4 + 255) & ~(size_t)255;
  unsigned* colcur = (unsigned*)(ws + off);   off += 256;
  unsigned* rcnt   = (unsigned*)(ws + off);   off += ((size_t)NREG * 4 + 255) & ~(size_t)255;
  bf16* g0 = (bf16*)(ws + off);               off += (size_t)NNODES * NCLS * 2;   // 12.8 MB
  // X region (51.2 MB): h1b [N][HID] bf16 during MLP; pb0/pb1 alias it (written
  // only after GEMM2 consumed h1b).
  char* X = ws + off;                         off += (size_t)NNODES * HID * 2;
  bf16* h1b = (bf16*)X;
  bf16* pb0 = (bf16*)X;
  bf16* pb1 = (bf16*)(X + (size_t)NNODES * NCLS * 2);
  int*  col = (int*)(ws + off);               off += ((size_t)E * 4 + 255) & ~(size_t)255;  // 12.8 MB
  unsigned* rdata = (unsigned*)(ws + off);    off += (size_t)NREG * RCAP * 4;     // 15.3 MB
  bf16* w1t = (bf16*)(ws + off);              off += ((size_t)HID * FIN * 2 + 255) & ~(size_t)255;
  bf16* w2t = (bf16*)(ws + off);              off += ((size_t)NCLS * HID * 2 + 255) & ~(size_t)255;

  // ---- CSR pass 1 ----
  hipMemsetAsync(rcnt, 0, (size_t)NREG * 4, stream);
  hipMemsetAsync(colcur, 0, 256, stream);
  csr_pass1<<<(E + TILE - 1) / TILE, 256, 0, stream>>>(src, dst, rcnt, rdata, E);

  // ---- weight transpose/convert (tiny) ----
  transpose_bf16<<<(FIN * HID + 255) / 256, 256, 0, stream>>>(w1, w1t, FIN, HID);
  transpose_bf16<<<(HID * NCLS + 255) / 256, 256, 0, stream>>>(w2, w2t, HID, NCLS);

  // ---- GEMM1 (A fetched once, 8-wave BM=128 pipelined dbuf) ----
  mfma_gemm1<<<(NNODES + 127) / 128, 512, 0, stream>>>(feat, w1t, b1, h1b, NNODES);

  // ---- CSR pass 2 (norm needed by GEMM2 epilogue) ----
  csr_pass2<<<NREG, 256, 0, stream>>>(rcnt, rdata, colcur, norm, rnorm,
                                      norm2a, startp, endp, col);

  // ---- GEMM2 with fused norm-scaling: writes g0 = norm .* h0 ----
  mfma_gemm2<<<(NNODES + 127) / 128, 256, 0, stream>>>(h1b, w2t, b2, norm, g0, NNODES);

  // ---- APPNP propagation (monolithic pull, 128B rows) ----
  const bf16* cur = g0;
  bf16* bufs[2] = {pb0, pb1};
  const int nblocks = (NNODES * 64 + 255) / 256;
  for (int k = 0; k < KSTEPS; ++k) {
    bf16* nxt = bufs[k & 1];
    appnp_pull_g<<<nblocks, 256, 0, stream>>>(cur, g0, norm2a, startp, endp, col, nxt);
    cur = nxt;
  }

  // ---- log_softmax (unscale by rnorm) ----
  log_softmax_k<<<(NNODES + 3) / 4, 256, 0, stream>>>(cur, rnorm, out, NNODES);
}